// Round 1
// baseline (431.728 us; speedup 1.0000x reference)
//
#include <hip/hip_runtime.h>
#include <stdint.h>

#define BLOCK 256
#define SEL0 46
#define SEL1 92
#define ASEL0 16
#define ASEL1 32
#define NNB 138           // SEL0+SEL1
#define NANG 48           // ASEL0+ASEL1
#define DDIM 282          // NNB + 3*NANG
#define HID 64
#define FEPS 1e-16f

__device__ __forceinline__ float mimg(float dx, float box, float ibox) {
    return dx - box * rintf(dx * ibox);   // jnp.round = round-half-even = rintf
}

template<int LEN>
__global__ __launch_bounds__(BLOCK)
void md_kernel(const float* __restrict__ xyz, const int* __restrict__ types,
               const void* __restrict__ boxp,
               const float* __restrict__ W0a, const float* __restrict__ B0a,
               const float* __restrict__ W1a, const float* __restrict__ B1a,
               const float* __restrict__ W2a, const float* __restrict__ B2a,
               const float* __restrict__ W0b, const float* __restrict__ B0b,
               const float* __restrict__ W1b, const float* __restrict__ B1b,
               const float* __restrict__ W2b, const float* __restrict__ B2b,
               float* __restrict__ out, int B, int N)
{
    const int atom = blockIdx.x;
    const int b = atom / N;
    const int i = atom - b * N;
    const int tid = threadIdx.x;

    __shared__ uint64_t skey[LEN];
    __shared__ float snd[NNB];
    __shared__ int   sni[NNB];
    __shared__ float sdesc[DDIM];
    __shared__ float sg[DDIM];
    __shared__ float sA[9];
    __shared__ float sh1[HID], sh2[HID], sdh2[HID], sdh1[HID];
    __shared__ float sG[9];
    __shared__ float sFi[3];
    __shared__ int sB0, sE1;

    // box_size may arrive as int32 (python int scalar) or float32; decode.
    int ib_test = ((const int*)boxp)[0];
    float box = (ib_test > 0 && ib_test < 1000000) ? (float)ib_test
                                                   : ((const float*)boxp)[0];
    float ibox = 1.0f / box;

    const float* X = xyz + (size_t)b * N * 3;
    const int*   T = types + (size_t)b * N;
    const int ti = T[i];
    const float xi = X[3*i+0], yi = X[3*i+1], zi = X[3*i+2];

    // ---- build sort keys: (type | dist_bits) << 32 | idx ; self/pad -> max ----
    for (int j = tid; j < LEN; j += BLOCK) {
        uint64_t k;
        if (j >= N || j == i) {
            k = 0xFFFFFFFFFFFFFFFFull;
        } else {
            float dx = mimg(xi - X[3*j+0], box, ibox);
            float dy = mimg(yi - X[3*j+1], box, ibox);
            float dz = mimg(zi - X[3*j+2], box, ibox);
            float d = sqrtf(dx*dx + dy*dy + dz*dz);
            uint32_t uk = __float_as_uint(d) | (T[j] ? 0x80000000u : 0u);
            k = ((uint64_t)uk << 32) | (uint32_t)j;
        }
        skey[j] = k;
    }

    // ---- bitonic sort ascending (exact distances, idx tie-break in low bits) ----
    for (int size = 2; size <= LEN; size <<= 1) {
        for (int stride = size >> 1; stride > 0; stride >>= 1) {
            __syncthreads();
            for (int t = tid; t < LEN/2; t += BLOCK) {
                int lo = ((t & ~(stride-1)) << 1) | (t & (stride-1));
                int hi = lo | stride;
                bool asc = (lo & size) == 0;
                uint64_t a = skey[lo], c = skey[hi];
                bool sw = asc ? (a > c) : (a < c);
                if (sw) { skey[lo] = c; skey[hi] = a; }
            }
        }
    }
    __syncthreads();

    if (tid == 0) {
        int lo = 0, hi = LEN;                       // first entry with type-1 bit
        while (lo < hi) { int m = (lo+hi)>>1; if (skey[m] >> 63) hi = m; else lo = m+1; }
        sB0 = lo;
        const uint64_t SENT = 0xFFFFFFFF00000000ull; // first sentinel (self/pad)
        hi = LEN;
        while (lo < hi) { int m = (lo+hi)>>1; if (skey[m] >= SENT) hi = m; else lo = m+1; }
        sE1 = lo;
    }
    if (tid < 9) sG[tid] = 0.0f;
    if (tid < 3) sFi[tid] = 0.0f;
    __syncthreads();
    const int nb0 = sB0, ne1 = sE1;

    // ---- neighbor tables + radial features 1/(d+eps) ----
    if (tid < NNB) {
        int pos; bool valid;
        if (tid < SEL0) { pos = tid;               valid = (pos < nb0); }
        else            { pos = nb0 + (tid - SEL0); valid = (pos < ne1); }
        float d = 1e30f; int j = -1;
        if (valid) {
            uint64_t k = skey[pos];
            d = __uint_as_float((uint32_t)(k >> 32) & 0x7FFFFFFFu);
            j = (int)(uint32_t)(k & 0xFFFFFFFFull);
        }
        snd[tid] = d; sni[tid] = j;
        sdesc[tid] = 1.0f / (d + FEPS);
    }
    __syncthreads();

    // ---- local frame (thread 0; keep state in registers for backward) ----
    float f_ld0=1.0f, f_ld1=1.0f; int f_j0=-1, f_j1=-1;
    float r0x=0,r0y=0,r0z=0, r1x=0,r1y=0,r1z=0;
    float u0x=0,u0y=0,u0z=0, u1x=0,u1y=0,u1z=0;
    float f_s=0, f_n2=1, f_n3=1;
    float e2x=0,e2y=0,e2z=0, e3x=0,e3y=0,e3z=0;
    if (tid == 0) {
        float da0 = snd[0],    db0 = snd[SEL0];
        float da1 = snd[1],    db1 = snd[SEL0+1];
        int   ja0 = sni[0],    jb0 = sni[SEL0];
        int   ja1 = sni[1],    jb1 = sni[SEL0+1];
        // reference: better = sd1 < lf_d (strict), elementwise per slot
        f_ld0 = (db0 < da0) ? db0 : da0;  f_j0 = (db0 < da0) ? jb0 : ja0;
        f_ld1 = (db1 < da1) ? db1 : da1;  f_j1 = (db1 < da1) ? jb1 : ja1;
        if (f_j0 < 0) f_j0 = i;  // safety, never expected
        if (f_j1 < 0) f_j1 = i;
        u0x = mimg(xi - X[3*f_j0+0], box, ibox);
        u0y = mimg(yi - X[3*f_j0+1], box, ibox);
        u0z = mimg(zi - X[3*f_j0+2], box, ibox);
        u1x = mimg(xi - X[3*f_j1+0], box, ibox);
        u1y = mimg(yi - X[3*f_j1+1], box, ibox);
        u1z = mimg(zi - X[3*f_j1+2], box, ibox);
        float id0 = 1.0f/(f_ld0 + FEPS), id1 = 1.0f/(f_ld1 + FEPS);
        r0x = u0x*id0; r0y = u0y*id0; r0z = u0z*id0;
        r1x = u1x*id1; r1y = u1y*id1; r1z = u1z*id1;
        f_s = r0x*r1x + r0y*r1y + r0z*r1z;
        float v2x = r1x - f_s*r0x, v2y = r1y - f_s*r0y, v2z = r1z - f_s*r0z;
        f_n2 = sqrtf(v2x*v2x + v2y*v2y + v2z*v2z);
        e2x = v2x/f_n2; e2y = v2y/f_n2; e2z = v2z/f_n2;
        float cx = r0y*r1z - r0z*r1y;
        float cy = r0z*r1x - r0x*r1z;
        float cz = r0x*r1y - r0y*r1x;
        f_n3 = sqrtf(cx*cx + cy*cy + cz*cz);
        e3x = cx/f_n3; e3y = cy/f_n3; e3z = cz/f_n3;
        sA[0]=r0x; sA[1]=r0y; sA[2]=r0z;
        sA[3]=e2x; sA[4]=e2y; sA[5]=e2z;
        sA[6]=e3x; sA[7]=e3y; sA[8]=e3z;
    }
    __syncthreads();

    // ---- angular features: f = (A . dm) / (d+eps)^2 ----
    if (tid < NANG) {
        int slot = (tid < ASEL0) ? tid : SEL0 + (tid - ASEL0);
        float d = snd[slot]; int j = sni[slot];
        float dx = 0, dy = 0, dz = 0;
        if (j >= 0) {
            dx = mimg(xi - X[3*j+0], box, ibox);
            dy = mimg(yi - X[3*j+1], box, ibox);
            dz = mimg(zi - X[3*j+2], box, ibox);
        }
        float de = d + FEPS;
        float q = 1.0f/(de*de);
        float wx = sA[0]*dx + sA[1]*dy + sA[2]*dz;
        float wy = sA[3]*dx + sA[4]*dy + sA[5]*dz;
        float wz = sA[6]*dx + sA[7]*dy + sA[8]*dz;
        sdesc[NNB + 3*tid + 0] = wx*q;
        sdesc[NNB + 3*tid + 1] = wy*q;
        sdesc[NNB + 3*tid + 2] = wz*q;
    }
    __syncthreads();

    // ---- MLP forward + backward (wave 0) ----
    const float* W0 = ti ? W0b : W0a;  const float* B0 = ti ? B0b : B0a;
    const float* W1 = ti ? W1b : W1a;  const float* B1 = ti ? B1b : B1a;
    const float* W2 = ti ? W2b : W2a;  const float* B2 = ti ? B2b : B2a;

    if (tid < HID) {
        float acc = B0[tid];
        for (int d = 0; d < DDIM; ++d) acc = fmaf(sdesc[d], W0[d*HID + tid], acc);
        sh1[tid] = tanhf(acc);
    }
    __syncthreads();
    if (tid < HID) {
        float acc = B1[tid];
        for (int m = 0; m < HID; ++m) acc = fmaf(sh1[m], W1[m*HID + tid], acc);
        sh2[tid] = tanhf(acc);
    }
    __syncthreads();
    if (tid < HID) {
        float w2 = W2[tid];
        float h2 = sh2[tid];
        float part = h2 * w2;
        #pragma unroll
        for (int o = 32; o > 0; o >>= 1) part += __shfl_down(part, o, 64);
        if (tid == 0) atomicAdd(&out[b], part + B2[0]);
        sdh2[tid] = (1.0f - h2*h2) * w2;
    }
    __syncthreads();
    if (tid < HID) {
        float acc = 0.0f;
        for (int m = 0; m < HID; ++m) acc = fmaf(W1[tid*HID + m], sdh2[m], acc);
        float h1 = sh1[tid];
        sdh1[tid] = (1.0f - h1*h1) * acc;
    }
    __syncthreads();
    for (int d = tid; d < DDIM; d += BLOCK) {
        float acc = 0.0f;
        for (int m = 0; m < HID; ++m) acc = fmaf(W0[d*HID + m], sdh1[m], acc);
        sg[d] = acc;
    }
    __syncthreads();

    // ---- gradient scatter: radial + angular direct terms; accumulate G ----
    float* Fout = out + B;
    if (tid < NNB) {
        float d = snd[tid]; int j = sni[tid];
        if (j >= 0) {
            float dx = mimg(xi - X[3*j+0], box, ibox);
            float dy = mimg(yi - X[3*j+1], box, ibox);
            float dz = mimg(zi - X[3*j+2], box, ibox);
            float gr = sg[tid];
            float de = d + FEPS;
            float coef = -gr / (d * de * de);      // d(1/(d+eps))/d(dm)
            float gx = coef*dx, gy = coef*dy, gz = coef*dz;
            int a = -1;
            if (tid < ASEL0) a = tid;
            else if (tid >= SEL0 && tid < SEL0 + ASEL1) a = ASEL0 + (tid - SEL0);
            if (a >= 0) {
                float q = 1.0f/(de*de);
                float gax = sg[NNB+3*a+0], gay = sg[NNB+3*a+1], gaz = sg[NNB+3*a+2];
                float wx = sA[0]*dx + sA[1]*dy + sA[2]*dz;
                float wy = sA[3]*dx + sA[4]*dy + sA[5]*dz;
                float wz = sA[6]*dx + sA[7]*dy + sA[8]*dz;
                float tx = sA[0]*gax + sA[3]*gay + sA[6]*gaz;  // A^T ga
                float ty = sA[1]*gax + sA[4]*gay + sA[7]*gaz;
                float tz = sA[2]*gax + sA[5]*gay + sA[8]*gaz;
                float gw = gax*wx + gay*wy + gaz*wz;
                float c2 = -2.0f * gw * q / (de * d);
                gx += q*tx + c2*dx;
                gy += q*ty + c2*dy;
                gz += q*tz + c2*dz;
                atomicAdd(&sG[0], gax*dx*q); atomicAdd(&sG[1], gax*dy*q); atomicAdd(&sG[2], gax*dz*q);
                atomicAdd(&sG[3], gay*dx*q); atomicAdd(&sG[4], gay*dy*q); atomicAdd(&sG[5], gay*dz*q);
                atomicAdd(&sG[6], gaz*dx*q); atomicAdd(&sG[7], gaz*dy*q); atomicAdd(&sG[8], gaz*dz*q);
            }
            float* Fj = Fout + 3*((size_t)b*N + j);
            atomicAdd(&Fj[0], gx); atomicAdd(&Fj[1], gy); atomicAdd(&Fj[2], gz);
            atomicAdd(&sFi[0], -gx); atomicAdd(&sFi[1], -gy); atomicAdd(&sFi[2], -gz);
        }
    }
    __syncthreads();

    // ---- frame backward (thread 0) ----
    if (tid == 0 && f_j0 >= 0) {
        float g0x=sG[0], g0y=sG[1], g0z=sG[2];
        float g2x=sG[3], g2y=sG[4], g2z=sG[5];
        float g3x=sG[6], g3y=sG[7], g3z=sG[8];
        // v3hat = c/n3 backward
        float d3 = g3x*e3x + g3y*e3y + g3z*e3z;
        float in3 = 1.0f/f_n3;
        float dcx = (g3x - d3*e3x)*in3;
        float dcy = (g3y - d3*e3y)*in3;
        float dcz = (g3z - d3*e3z)*in3;
        // c = r0 x r1 backward: gr0 += r1 x dc ; gr1 += dc x r0
        float gr0x = r1y*dcz - r1z*dcy;
        float gr0y = r1z*dcx - r1x*dcz;
        float gr0z = r1x*dcy - r1y*dcx;
        float gr1x = dcy*r0z - dcz*r0y;
        float gr1y = dcz*r0x - dcx*r0z;
        float gr1z = dcx*r0y - dcy*r0x;
        // v2hat backward
        float d2 = g2x*e2x + g2y*e2y + g2z*e2z;
        float in2 = 1.0f/f_n2;
        float dvx = (g2x - d2*e2x)*in2;
        float dvy = (g2y - d2*e2y)*in2;
        float dvz = (g2z - d2*e2z)*in2;
        // v2 = r1 - s*r0, s = r0.r1
        gr1x += dvx; gr1y += dvy; gr1z += dvz;
        gr0x -= f_s*dvx; gr0y -= f_s*dvy; gr0z -= f_s*dvz;
        float dss = -(dvx*r0x + dvy*r0y + dvz*r0z);
        gr0x += dss*r1x; gr0y += dss*r1y; gr0z += dss*r1z;
        gr1x += dss*r0x; gr1y += dss*r0y; gr1z += dss*r0z;
        // A row 0 direct
        gr0x += g0x; gr0y += g0y; gr0z += g0z;
        // r = u/(ld+eps), ld = |u|
        float de0 = f_ld0 + FEPS;
        float dot0 = gr0x*u0x + gr0y*u0y + gr0z*u0z;
        float k0 = dot0 / (f_ld0 * de0 * de0);
        float gu0x = gr0x/de0 - k0*u0x;
        float gu0y = gr0y/de0 - k0*u0y;
        float gu0z = gr0z/de0 - k0*u0z;
        float de1 = f_ld1 + FEPS;
        float dot1 = gr1x*u1x + gr1y*u1y + gr1z*u1z;
        float k1 = dot1 / (f_ld1 * de1 * de1);
        float gu1x = gr1x/de1 - k1*u1x;
        float gu1y = gr1y/de1 - k1*u1y;
        float gu1z = gr1z/de1 - k1*u1z;
        float* Fj0 = Fout + 3*((size_t)b*N + f_j0);
        atomicAdd(&Fj0[0], gu0x); atomicAdd(&Fj0[1], gu0y); atomicAdd(&Fj0[2], gu0z);
        float* Fj1 = Fout + 3*((size_t)b*N + f_j1);
        atomicAdd(&Fj1[0], gu1x); atomicAdd(&Fj1[1], gu1y); atomicAdd(&Fj1[2], gu1z);
        sFi[0] -= gu0x + gu1x;
        sFi[1] -= gu0y + gu1y;
        sFi[2] -= gu0z + gu1z;
    }
    __syncthreads();
    if (tid < 3) {
        atomicAdd(&Fout[3*((size_t)b*N + i) + tid], sFi[tid]);
    }
}

extern "C" void kernel_launch(void* const* d_in, const int* in_sizes, int n_in,
                              void* d_out, int out_size, void* d_ws, size_t ws_size,
                              hipStream_t stream) {
    const float* xyz  = (const float*)d_in[0];
    const int*   types = (const int*)d_in[1];
    const void*  boxp = d_in[2];
    int BN = in_sizes[1];              // B*N
    int B = out_size - 3*BN;           // out = energy(B) + forces(3*B*N)
    if (B < 1) B = 1;
    int N = BN / B;
    hipMemsetAsync(d_out, 0, (size_t)out_size * sizeof(float), stream);
    md_kernel<2048><<<dim3(BN), dim3(BLOCK), 0, stream>>>(
        xyz, types, boxp,
        (const float*)d_in[3],  (const float*)d_in[4],
        (const float*)d_in[5],  (const float*)d_in[6],
        (const float*)d_in[7],  (const float*)d_in[8],
        (const float*)d_in[9],  (const float*)d_in[10],
        (const float*)d_in[11], (const float*)d_in[12],
        (const float*)d_in[13], (const float*)d_in[14],
        (float*)d_out, B, N);
}

// Round 2
// 331.497 us; speedup vs baseline: 1.3024x; 1.3024x over previous
//
#include <hip/hip_runtime.h>
#include <stdint.h>
#include <math.h>

#define BLOCK 256
#define SEL0 46
#define SEL1 92
#define ASEL0 16
#define ASEL1 32
#define NNB 138           // SEL0+SEL1
#define NANG 48           // ASEL0+ASEL1
#define DDIM 282          // NNB + 3*NANG
#define HID 64
#define FEPS 1e-16f
#define NPT 8             // atoms per thread (N=2048 / BLOCK)

__device__ __forceinline__ float mimg(float dx, float box, float ibox) {
    return dx - box * rintf(dx * ibox);   // jnp.round = round-half-even = rintf
}

template<int LEN>
__global__ __launch_bounds__(BLOCK)
void md_kernel(const float* __restrict__ xyz, const int* __restrict__ types,
               const void* __restrict__ boxp,
               const float* __restrict__ W0a, const float* __restrict__ B0a,
               const float* __restrict__ W1a, const float* __restrict__ B1a,
               const float* __restrict__ W2a, const float* __restrict__ B2a,
               const float* __restrict__ W0b, const float* __restrict__ B0b,
               const float* __restrict__ W1b, const float* __restrict__ B1b,
               const float* __restrict__ W2b, const float* __restrict__ B2b,
               float* __restrict__ out, int B, int N)
{
    const int atom = blockIdx.x;
    const int b = atom / N;
    const int i = atom - b * N;
    const int tid = threadIdx.x;

    __shared__ uint64_t skey[LEN];
    __shared__ float snd[NNB];
    __shared__ int   sni[NNB];
    __shared__ float sdesc[DDIM];
    __shared__ float sg[DDIM];
    __shared__ float sA[9];
    __shared__ float sh1[HID], sh2[HID], sdh2[HID], sdh1[HID];
    __shared__ float sG[9];
    __shared__ float sFi[3];
    __shared__ int sB0, sE1;
    __shared__ int sCnt0, sCnt1, sTot1, sM;

    // box_size may arrive as int32 (python int scalar) or float32; decode.
    int ib_test = ((const int*)boxp)[0];
    float box = (ib_test > 0 && ib_test < 1000000) ? (float)ib_test
                                                   : ((const float*)boxp)[0];
    float ibox = 1.0f / box;

    const float* X = xyz + (size_t)b * N * 3;
    const int*   T = types + (size_t)b * N;
    const int ti = T[i];
    const float xi = X[3*i+0], yi = X[3*i+1], zi = X[3*i+2];

    // ---- per-thread distance keys in registers: rk = typebit<<31 | dist_bits ----
    uint32_t rk[NPT];
    #pragma unroll
    for (int jj = 0; jj < NPT; ++jj) {
        int j = jj * BLOCK + tid;
        uint32_t k = 0x7FFFFFFFu;           // self / pad: never below any threshold
        if (j < N && j != i) {
            float dx = mimg(xi - X[3*j+0], box, ibox);
            float dy = mimg(yi - X[3*j+1], box, ibox);
            float dz = mimg(zi - X[3*j+2], box, ibox);
            float d = sqrtf(dx*dx + dy*dy + dz*dz);
            k = __float_as_uint(d) | (T[j] ? 0x80000000u : 0u);
        }
        rk[jj] = k;
    }

    // ---- per-type totals (for caps) ----
    if (tid == 0) { sTot1 = 0; }
    __syncthreads();
    {
        uint32_t t1 = 0;
        #pragma unroll
        for (int jj = 0; jj < NPT; ++jj) t1 += (rk[jj] >> 31);
        #pragma unroll
        for (int o = 32; o > 0; o >>= 1) t1 += __shfl_down(t1, o, 64);
        if ((tid & 63) == 0 && t1) atomicAdd(&sTot1, (int)t1);
    }
    __syncthreads();
    const int tot1 = sTot1;
    const int tot0 = (N - 1) - tot1;
    const int need0 = min(SEL0, tot0);
    const int need1 = min(SEL1, tot1);

    // ---- initial radius from uniform-density estimate ----
    float vol = box * box * box;
    float r0e = cbrtf((3.0f * SEL0 * vol) / (4.0f * 3.14159265f * fmaxf((float)tot0, 1.0f)));
    float r1e = cbrtf((3.0f * SEL1 * vol) / (4.0f * 3.14159265f * fmaxf((float)tot1, 1.0f)));
    float R = 1.09f * fmaxf(r0e, r1e);

    // ---- grow R until candidate counts suffice (uniform control flow) ----
    uint32_t Rb = __float_as_uint(R);
    for (int it = 0; it < 24; ++it) {
        if (tid == 0) { sCnt0 = 0; sCnt1 = 0; }
        __syncthreads();
        uint32_t c0 = 0, c1 = 0;
        #pragma unroll
        for (int jj = 0; jj < NPT; ++jj) {
            uint32_t k = rk[jj];
            c0 += (k < Rb);
            c1 += ((k >= 0x80000000u) && ((k & 0x7FFFFFFFu) < Rb));
        }
        uint32_t packed = c0 | (c1 << 16);
        #pragma unroll
        for (int o = 32; o > 0; o >>= 1) packed += __shfl_down(packed, o, 64);
        if ((tid & 63) == 0) {
            atomicAdd(&sCnt0, (int)(packed & 0xFFFFu));
            atomicAdd(&sCnt1, (int)(packed >> 16));
        }
        __syncthreads();
        if (sCnt0 >= need0 && sCnt1 >= need1) break;
        R *= 1.25f;
        Rb = __float_as_uint(R);
        __syncthreads();
    }

    // ---- compact candidates into LDS ----
    if (tid == 0) sM = 0;
    __syncthreads();
    #pragma unroll
    for (int jj = 0; jj < NPT; ++jj) {
        uint32_t k = rk[jj];
        bool in0 = (k < Rb);
        bool in1 = ((k >= 0x80000000u) && ((k & 0x7FFFFFFFu) < Rb));
        if (in0 || in1) {
            int pos = atomicAdd(&sM, 1);
            if (pos < LEN) skey[pos] = ((uint64_t)k << 32) | (uint32_t)(jj * BLOCK + tid);
        }
    }
    __syncthreads();
    int M = min(sM, LEN);
    int Mp = 4; while (Mp < M) Mp <<= 1;      // next pow2 >= M
    for (int p = M + tid; p < Mp; p += BLOCK) skey[p] = 0xFFFFFFFFFFFFFFFFull;

    // ---- bitonic sort ascending over Mp candidates ----
    for (int size = 2; size <= Mp; size <<= 1) {
        for (int stride = size >> 1; stride > 0; stride >>= 1) {
            __syncthreads();
            for (int t = tid; t < Mp/2; t += BLOCK) {
                int lo = ((t & ~(stride-1)) << 1) | (t & (stride-1));
                int hi = lo | stride;
                bool asc = (lo & size) == 0;
                uint64_t a = skey[lo], c = skey[hi];
                bool sw = asc ? (a > c) : (a < c);
                if (sw) { skey[lo] = c; skey[hi] = a; }
            }
        }
    }
    __syncthreads();

    if (tid == 0) {
        int lo = 0, hi = Mp;                        // first entry with type-1 bit
        while (lo < hi) { int m = (lo+hi)>>1; if (skey[m] >> 63) hi = m; else lo = m+1; }
        sB0 = lo;
        const uint64_t SENT = 0xFFFFFFFF00000000ull; // first sentinel
        hi = Mp;
        while (lo < hi) { int m = (lo+hi)>>1; if (skey[m] >= SENT) hi = m; else lo = m+1; }
        sE1 = lo;
    }
    if (tid < 9) sG[tid] = 0.0f;
    if (tid < 3) sFi[tid] = 0.0f;
    __syncthreads();
    const int nb0 = sB0, ne1 = sE1;

    // ---- neighbor tables + radial features 1/(d+eps) ----
    if (tid < NNB) {
        int pos; bool valid;
        if (tid < SEL0) { pos = tid;               valid = (pos < nb0); }
        else            { pos = nb0 + (tid - SEL0); valid = (pos < ne1); }
        float d = 1e30f; int j = -1;
        if (valid) {
            uint64_t k = skey[pos];
            d = __uint_as_float((uint32_t)(k >> 32) & 0x7FFFFFFFu);
            j = (int)(uint32_t)(k & 0xFFFFFFFFull);
        }
        snd[tid] = d; sni[tid] = j;
        sdesc[tid] = 1.0f / (d + FEPS);
    }
    __syncthreads();

    // ---- local frame (thread 0; keep state in registers for backward) ----
    float f_ld0=1.0f, f_ld1=1.0f; int f_j0=-1, f_j1=-1;
    float r0x=0,r0y=0,r0z=0, r1x=0,r1y=0,r1z=0;
    float u0x=0,u0y=0,u0z=0, u1x=0,u1y=0,u1z=0;
    float f_s=0, f_n2=1, f_n3=1;
    float e2x=0,e2y=0,e2z=0, e3x=0,e3y=0,e3z=0;
    if (tid == 0) {
        float da0 = snd[0],    db0 = snd[SEL0];
        float da1 = snd[1],    db1 = snd[SEL0+1];
        int   ja0 = sni[0],    jb0 = sni[SEL0];
        int   ja1 = sni[1],    jb1 = sni[SEL0+1];
        f_ld0 = (db0 < da0) ? db0 : da0;  f_j0 = (db0 < da0) ? jb0 : ja0;
        f_ld1 = (db1 < da1) ? db1 : da1;  f_j1 = (db1 < da1) ? jb1 : ja1;
        if (f_j0 < 0) f_j0 = i;
        if (f_j1 < 0) f_j1 = i;
        u0x = mimg(xi - X[3*f_j0+0], box, ibox);
        u0y = mimg(yi - X[3*f_j0+1], box, ibox);
        u0z = mimg(zi - X[3*f_j0+2], box, ibox);
        u1x = mimg(xi - X[3*f_j1+0], box, ibox);
        u1y = mimg(yi - X[3*f_j1+1], box, ibox);
        u1z = mimg(zi - X[3*f_j1+2], box, ibox);
        float id0 = 1.0f/(f_ld0 + FEPS), id1 = 1.0f/(f_ld1 + FEPS);
        r0x = u0x*id0; r0y = u0y*id0; r0z = u0z*id0;
        r1x = u1x*id1; r1y = u1y*id1; r1z = u1z*id1;
        f_s = r0x*r1x + r0y*r1y + r0z*r1z;
        float v2x = r1x - f_s*r0x, v2y = r1y - f_s*r0y, v2z = r1z - f_s*r0z;
        f_n2 = sqrtf(v2x*v2x + v2y*v2y + v2z*v2z);
        e2x = v2x/f_n2; e2y = v2y/f_n2; e2z = v2z/f_n2;
        float cx = r0y*r1z - r0z*r1y;
        float cy = r0z*r1x - r0x*r1z;
        float cz = r0x*r1y - r0y*r1x;
        f_n3 = sqrtf(cx*cx + cy*cy + cz*cz);
        e3x = cx/f_n3; e3y = cy/f_n3; e3z = cz/f_n3;
        sA[0]=r0x; sA[1]=r0y; sA[2]=r0z;
        sA[3]=e2x; sA[4]=e2y; sA[5]=e2z;
        sA[6]=e3x; sA[7]=e3y; sA[8]=e3z;
    }
    __syncthreads();

    // ---- angular features: f = (A . dm) / (d+eps)^2 ----
    if (tid < NANG) {
        int slot = (tid < ASEL0) ? tid : SEL0 + (tid - ASEL0);
        float d = snd[slot]; int j = sni[slot];
        float dx = 0, dy = 0, dz = 0;
        if (j >= 0) {
            dx = mimg(xi - X[3*j+0], box, ibox);
            dy = mimg(yi - X[3*j+1], box, ibox);
            dz = mimg(zi - X[3*j+2], box, ibox);
        }
        float de = d + FEPS;
        float q = 1.0f/(de*de);
        float wx = sA[0]*dx + sA[1]*dy + sA[2]*dz;
        float wy = sA[3]*dx + sA[4]*dy + sA[5]*dz;
        float wz = sA[6]*dx + sA[7]*dy + sA[8]*dz;
        sdesc[NNB + 3*tid + 0] = wx*q;
        sdesc[NNB + 3*tid + 1] = wy*q;
        sdesc[NNB + 3*tid + 2] = wz*q;
    }
    __syncthreads();

    // ---- MLP forward + backward (wave 0) ----
    const float* W0 = ti ? W0b : W0a;  const float* B0 = ti ? B0b : B0a;
    const float* W1 = ti ? W1b : W1a;  const float* B1 = ti ? B1b : B1a;
    const float* W2 = ti ? W2b : W2a;  const float* B2 = ti ? B2b : B2a;

    if (tid < HID) {
        float acc = B0[tid];
        for (int d = 0; d < DDIM; ++d) acc = fmaf(sdesc[d], W0[d*HID + tid], acc);
        sh1[tid] = tanhf(acc);
    }
    __syncthreads();
    if (tid < HID) {
        float acc = B1[tid];
        for (int m = 0; m < HID; ++m) acc = fmaf(sh1[m], W1[m*HID + tid], acc);
        sh2[tid] = tanhf(acc);
    }
    __syncthreads();
    if (tid < HID) {
        float w2 = W2[tid];
        float h2 = sh2[tid];
        float part = h2 * w2;
        #pragma unroll
        for (int o = 32; o > 0; o >>= 1) part += __shfl_down(part, o, 64);
        if (tid == 0) atomicAdd(&out[b], part + B2[0]);
        sdh2[tid] = (1.0f - h2*h2) * w2;
    }
    __syncthreads();
    if (tid < HID) {
        float acc = 0.0f;
        for (int m = 0; m < HID; ++m) acc = fmaf(W1[tid*HID + m], sdh2[m], acc);
        float h1 = sh1[tid];
        sdh1[tid] = (1.0f - h1*h1) * acc;
    }
    __syncthreads();
    for (int d = tid; d < DDIM; d += BLOCK) {
        float acc = 0.0f;
        for (int m = 0; m < HID; ++m) acc = fmaf(W0[d*HID + m], sdh1[m], acc);
        sg[d] = acc;
    }
    __syncthreads();

    // ---- gradient scatter: radial + angular direct terms; accumulate G ----
    float* Fout = out + B;
    if (tid < NNB) {
        float d = snd[tid]; int j = sni[tid];
        if (j >= 0) {
            float dx = mimg(xi - X[3*j+0], box, ibox);
            float dy = mimg(yi - X[3*j+1], box, ibox);
            float dz = mimg(zi - X[3*j+2], box, ibox);
            float gr = sg[tid];
            float de = d + FEPS;
            float coef = -gr / (d * de * de);
            float gx = coef*dx, gy = coef*dy, gz = coef*dz;
            int a = -1;
            if (tid < ASEL0) a = tid;
            else if (tid >= SEL0 && tid < SEL0 + ASEL1) a = ASEL0 + (tid - SEL0);
            if (a >= 0) {
                float q = 1.0f/(de*de);
                float gax = sg[NNB+3*a+0], gay = sg[NNB+3*a+1], gaz = sg[NNB+3*a+2];
                float wx = sA[0]*dx + sA[1]*dy + sA[2]*dz;
                float wy = sA[3]*dx + sA[4]*dy + sA[5]*dz;
                float wz = sA[6]*dx + sA[7]*dy + sA[8]*dz;
                float tx = sA[0]*gax + sA[3]*gay + sA[6]*gaz;
                float ty = sA[1]*gax + sA[4]*gay + sA[7]*gaz;
                float tz = sA[2]*gax + sA[5]*gay + sA[8]*gaz;
                float gw = gax*wx + gay*wy + gaz*wz;
                float c2 = -2.0f * gw * q / (de * d);
                gx += q*tx + c2*dx;
                gy += q*ty + c2*dy;
                gz += q*tz + c2*dz;
                atomicAdd(&sG[0], gax*dx*q); atomicAdd(&sG[1], gax*dy*q); atomicAdd(&sG[2], gax*dz*q);
                atomicAdd(&sG[3], gay*dx*q); atomicAdd(&sG[4], gay*dy*q); atomicAdd(&sG[5], gay*dz*q);
                atomicAdd(&sG[6], gaz*dx*q); atomicAdd(&sG[7], gaz*dy*q); atomicAdd(&sG[8], gaz*dz*q);
            }
            float* Fj = Fout + 3*((size_t)b*N + j);
            atomicAdd(&Fj[0], gx); atomicAdd(&Fj[1], gy); atomicAdd(&Fj[2], gz);
            atomicAdd(&sFi[0], -gx); atomicAdd(&sFi[1], -gy); atomicAdd(&sFi[2], -gz);
        }
    }
    __syncthreads();

    // ---- frame backward (thread 0) ----
    if (tid == 0 && f_j0 >= 0) {
        float g0x=sG[0], g0y=sG[1], g0z=sG[2];
        float g2x=sG[3], g2y=sG[4], g2z=sG[5];
        float g3x=sG[6], g3y=sG[7], g3z=sG[8];
        float d3 = g3x*e3x + g3y*e3y + g3z*e3z;
        float in3 = 1.0f/f_n3;
        float dcx = (g3x - d3*e3x)*in3;
        float dcy = (g3y - d3*e3y)*in3;
        float dcz = (g3z - d3*e3z)*in3;
        float gr0x = r1y*dcz - r1z*dcy;
        float gr0y = r1z*dcx - r1x*dcz;
        float gr0z = r1x*dcy - r1y*dcx;
        float gr1x = dcy*r0z - dcz*r0y;
        float gr1y = dcz*r0x - dcx*r0z;
        float gr1z = dcx*r0y - dcy*r0x;
        float d2 = g2x*e2x + g2y*e2y + g2z*e2z;
        float in2 = 1.0f/f_n2;
        float dvx = (g2x - d2*e2x)*in2;
        float dvy = (g2y - d2*e2y)*in2;
        float dvz = (g2z - d2*e2z)*in2;
        gr1x += dvx; gr1y += dvy; gr1z += dvz;
        gr0x -= f_s*dvx; gr0y -= f_s*dvy; gr0z -= f_s*dvz;
        float dss = -(dvx*r0x + dvy*r0y + dvz*r0z);
        gr0x += dss*r1x; gr0y += dss*r1y; gr0z += dss*r1z;
        gr1x += dss*r0x; gr1y += dss*r0y; gr1z += dss*r0z;
        gr0x += g0x; gr0y += g0y; gr0z += g0z;
        float de0 = f_ld0 + FEPS;
        float dot0 = gr0x*u0x + gr0y*u0y + gr0z*u0z;
        float k0 = dot0 / (f_ld0 * de0 * de0);
        float gu0x = gr0x/de0 - k0*u0x;
        float gu0y = gr0y/de0 - k0*u0y;
        float gu0z = gr0z/de0 - k0*u0z;
        float de1 = f_ld1 + FEPS;
        float dot1 = gr1x*u1x + gr1y*u1y + gr1z*u1z;
        float k1 = dot1 / (f_ld1 * de1 * de1);
        float gu1x = gr1x/de1 - k1*u1x;
        float gu1y = gr1y/de1 - k1*u1y;
        float gu1z = gr1z/de1 - k1*u1z;
        float* Fj0 = Fout + 3*((size_t)b*N + f_j0);
        atomicAdd(&Fj0[0], gu0x); atomicAdd(&Fj0[1], gu0y); atomicAdd(&Fj0[2], gu0z);
        float* Fj1 = Fout + 3*((size_t)b*N + f_j1);
        atomicAdd(&Fj1[0], gu1x); atomicAdd(&Fj1[1], gu1y); atomicAdd(&Fj1[2], gu1z);
        sFi[0] -= gu0x + gu1x;
        sFi[1] -= gu0y + gu1y;
        sFi[2] -= gu0z + gu1z;
    }
    __syncthreads();
    if (tid < 3) {
        atomicAdd(&Fout[3*((size_t)b*N + i) + tid], sFi[tid]);
    }
}

extern "C" void kernel_launch(void* const* d_in, const int* in_sizes, int n_in,
                              void* d_out, int out_size, void* d_ws, size_t ws_size,
                              hipStream_t stream) {
    const float* xyz  = (const float*)d_in[0];
    const int*   types = (const int*)d_in[1];
    const void*  boxp = d_in[2];
    int BN = in_sizes[1];              // B*N
    int B = out_size - 3*BN;           // out = energy(B) + forces(3*B*N)
    if (B < 1) B = 1;
    int N = BN / B;
    hipMemsetAsync(d_out, 0, (size_t)out_size * sizeof(float), stream);
    md_kernel<2048><<<dim3(BN), dim3(BLOCK), 0, stream>>>(
        xyz, types, boxp,
        (const float*)d_in[3],  (const float*)d_in[4],
        (const float*)d_in[5],  (const float*)d_in[6],
        (const float*)d_in[7],  (const float*)d_in[8],
        (const float*)d_in[9],  (const float*)d_in[10],
        (const float*)d_in[11], (const float*)d_in[12],
        (const float*)d_in[13], (const float*)d_in[14],
        (float*)d_out, B, N);
}

// Round 3
// 323.682 us; speedup vs baseline: 1.3338x; 1.0241x over previous
//
#include <hip/hip_runtime.h>
#include <stdint.h>
#include <math.h>

#define BLOCK 256
#define SEL0 46
#define SEL1 92
#define ASEL0 16
#define ASEL1 32
#define NNB 138           // SEL0+SEL1
#define NANG 48           // ASEL0+ASEL1
#define DDIM 282          // NNB + 3*NANG
#define HID 64
#define FEPS 1e-16f
#define NPT 8             // atoms per thread (N=2048 / BLOCK)
#define CAP 128           // per-type candidate cap (wave-sortable)

__device__ __forceinline__ float mimg(float dx, float box, float ibox) {
    return dx - box * rintf(dx * ibox);   // jnp.round = round-half-even = rintf
}

__global__ __launch_bounds__(BLOCK)
void md_kernel(const float* __restrict__ xyz, const int* __restrict__ types,
               const void* __restrict__ boxp,
               const float* __restrict__ W0a, const float* __restrict__ B0a,
               const float* __restrict__ W1a, const float* __restrict__ B1a,
               const float* __restrict__ W2a, const float* __restrict__ B2a,
               const float* __restrict__ W0b, const float* __restrict__ B0b,
               const float* __restrict__ W1b, const float* __restrict__ B1b,
               const float* __restrict__ W2b, const float* __restrict__ B2b,
               float* __restrict__ out, int B, int N)
{
    const int atom = blockIdx.x;
    const int b = atom / N;
    const int i = atom - b * N;
    const int tid = threadIdx.x;
    const int wv = tid >> 6, lane = tid & 63;

    __shared__ unsigned long long A0[CAP], A1[CAP];
    __shared__ float snd[NNB];
    __shared__ int   sni[NNB];
    __shared__ float sdesc[DDIM];
    __shared__ float sg[DDIM];
    __shared__ float sA[9];
    __shared__ float sh1[HID], sh2[HID], sdh2[HID], sdh1[HID];
    __shared__ float spart[4][HID];
    __shared__ float sG[9];
    __shared__ float sFi[3];
    __shared__ int sCnt0, sCnt1, sTot1;

    // box_size may arrive as int32 (python int scalar) or float32; decode.
    int ib_test = ((const int*)boxp)[0];
    float box = (ib_test > 0 && ib_test < 1000000) ? (float)ib_test
                                                   : ((const float*)boxp)[0];
    float ibox = 1.0f / box;

    const float* X = xyz + (size_t)b * N * 3;
    const int*   T = types + (size_t)b * N;
    const int ti = T[i];
    const float xi = X[3*i+0], yi = X[3*i+1], zi = X[3*i+2];

    // ---- per-thread distance keys in registers: rk = typebit<<31 | dist_bits ----
    uint32_t rk[NPT];
    #pragma unroll
    for (int jj = 0; jj < NPT; ++jj) {
        int j = jj * BLOCK + tid;
        uint32_t k = 0x7FFFFFFFu;           // self / pad: below no threshold
        if (j < N && j != i) {
            float dx = mimg(xi - X[3*j+0], box, ibox);
            float dy = mimg(yi - X[3*j+1], box, ibox);
            float dz = mimg(zi - X[3*j+2], box, ibox);
            float d = sqrtf(dx*dx + dy*dy + dz*dz);
            k = __float_as_uint(d) | (T[j] ? 0x80000000u : 0u);
        }
        rk[jj] = k;
    }

    // ---- per-type totals ----
    if (tid == 0) { sTot1 = 0; }
    __syncthreads();
    {
        uint32_t t1 = 0;
        #pragma unroll
        for (int jj = 0; jj < NPT; ++jj) t1 += (rk[jj] >> 31);
        #pragma unroll
        for (int o = 32; o > 0; o >>= 1) t1 += __shfl_down(t1, o, 64);
        if (lane == 0 && t1) atomicAdd(&sTot1, (int)t1);
    }
    __syncthreads();
    const int tot1 = sTot1;
    const int tot0 = (N - 1) - tot1;
    const int need0 = min(SEL0, tot0);
    const int need1 = min(SEL1, tot1);

    // ---- per-type radii via bisection: need_t <= count_t <= CAP ----
    const float vol = box * box * box;
    const float c43pi = 4.18879020f;   // 4/3*pi
    float R0 = cbrtf(0.5f * (need0 + CAP) * vol / (c43pi * fmaxf((float)tot0, 1.0f)));
    float R1 = cbrtf(0.5f * (need1 + CAP) * vol / (c43pi * fmaxf((float)tot1, 1.0f)));
    uint32_t Rb0 = __float_as_uint(R0), Rb1 = __float_as_uint(R1);
    float lo0 = 0.0f, hi0 = -1.0f, lo1 = 0.0f, hi1 = -1.0f;
    for (int it = 0; it < 20; ++it) {
        if (tid == 0) { sCnt0 = 0; sCnt1 = 0; }
        __syncthreads();
        uint32_t c0 = 0, c1 = 0;
        #pragma unroll
        for (int jj = 0; jj < NPT; ++jj) {
            uint32_t k = rk[jj];
            c0 += ((k < 0x80000000u) && (k < Rb0));
            c1 += ((k >= 0x80000000u) && ((k & 0x7FFFFFFFu) < Rb1));
        }
        uint32_t packed = c0 | (c1 << 16);
        #pragma unroll
        for (int o = 32; o > 0; o >>= 1) packed += __shfl_down(packed, o, 64);
        if (lane == 0 && packed) {
            atomicAdd(&sCnt0, (int)(packed & 0xFFFFu));
            atomicAdd(&sCnt1, (int)(packed >> 16));
        }
        __syncthreads();
        int cc0 = sCnt0, cc1 = sCnt1;
        bool done0 = (cc0 >= need0 && cc0 <= CAP);
        bool done1 = (cc1 >= need1 && cc1 <= CAP);
        if (done0 && done1) break;
        if (!done0) {
            if (cc0 < need0) { lo0 = R0; R0 = (hi0 > 0.0f) ? 0.5f*(lo0+hi0) : R0*1.3f; }
            else             { hi0 = R0; R0 = 0.5f*(lo0+hi0); }
            Rb0 = __float_as_uint(R0);
        }
        if (!done1) {
            if (cc1 < need1) { lo1 = R1; R1 = (hi1 > 0.0f) ? 0.5f*(lo1+hi1) : R1*1.3f; }
            else             { hi1 = R1; R1 = 0.5f*(lo1+hi1); }
            Rb1 = __float_as_uint(R1);
        }
        __syncthreads();
    }

    // ---- compact per-type candidates into A0 / A1 ----
    if (tid == 0) { sCnt0 = 0; sCnt1 = 0; }
    __syncthreads();
    #pragma unroll
    for (int jj = 0; jj < NPT; ++jj) {
        uint32_t k = rk[jj];
        uint32_t idx = (uint32_t)(jj * BLOCK + tid);
        if (k < 0x80000000u) {
            if (k < Rb0) {
                int pos = atomicAdd(&sCnt0, 1);
                if (pos < CAP) A0[pos] = ((unsigned long long)k << 32) | idx;
            }
        } else {
            uint32_t kk = k & 0x7FFFFFFFu;
            if (kk < Rb1) {
                int pos = atomicAdd(&sCnt1, 1);
                if (pos < CAP) A1[pos] = ((unsigned long long)kk << 32) | idx;
            }
        }
    }
    __syncthreads();
    const int c0 = min(sCnt0, CAP);
    const int c1 = min(sCnt1, CAP);
    if (tid < CAP) { if (tid >= c0) A0[tid] = ~0ull; }
    else { int t2 = tid - CAP; if (t2 >= c1) A1[t2] = ~0ull; }
    __syncthreads();

    // ---- wave-level register bitonic sort: wave0 -> A0, wave1 -> A1 ----
    if (wv < 2) {
        unsigned long long* A = (wv == 0) ? A0 : A1;
        unsigned long long v0 = A[lane], v1 = A[lane + 64];
        #pragma unroll
        for (int size = 2; size <= 128; size <<= 1) {
            #pragma unroll
            for (int stride = 64; stride > 0; stride >>= 1) {
                if (stride >= size) continue;
                if (stride == 64) {
                    // positions lane & lane+64; (p&128)==0 -> ascending
                    unsigned long long mn = v0 < v1 ? v0 : v1;
                    unsigned long long mx = v0 < v1 ? v1 : v0;
                    v0 = mn; v1 = mx;
                } else {
                    bool keep_lo = (lane & stride) == 0;
                    bool asc0 = ((lane & size) == 0);
                    bool asc1 = (((lane + 64) & size) == 0);
                    unsigned long long o0 = __shfl_xor(v0, stride, 64);
                    unsigned long long o1 = __shfl_xor(v1, stride, 64);
                    v0 = (asc0 == keep_lo) ? (v0 < o0 ? v0 : o0) : (v0 > o0 ? v0 : o0);
                    v1 = (asc1 == keep_lo) ? (v1 < o1 ? v1 : o1) : (v1 > o1 ? v1 : o1);
                }
            }
        }
        A[lane] = v0; A[lane + 64] = v1;
    }
    if (tid < 9) sG[tid] = 0.0f;
    if (tid < 3) sFi[tid] = 0.0f;
    __syncthreads();

    // ---- neighbor tables + radial features 1/(d+eps) ----
    if (tid < NNB) {
        unsigned long long k; bool valid;
        if (tid < SEL0) { valid = (tid < c0); k = A0[tid]; }
        else            { int t2 = tid - SEL0; valid = (t2 < c1); k = A1[t2]; }
        float d = 1e30f; int j = -1;
        if (valid) {
            d = __uint_as_float((uint32_t)(k >> 32));
            j = (int)(uint32_t)(k & 0xFFFFFFFFull);
        }
        snd[tid] = d; sni[tid] = j;
        sdesc[tid] = 1.0f / (d + FEPS);
    }
    __syncthreads();

    // ---- local frame (thread 0; keep state in registers for backward) ----
    float f_ld0=1.0f, f_ld1=1.0f; int f_j0=-1, f_j1=-1;
    float r0x=0,r0y=0,r0z=0, r1x=0,r1y=0,r1z=0;
    float u0x=0,u0y=0,u0z=0, u1x=0,u1y=0,u1z=0;
    float f_s=0, f_n2=1, f_n3=1;
    float e2x=0,e2y=0,e2z=0, e3x=0,e3y=0,e3z=0;
    if (tid == 0) {
        float da0 = snd[0],    db0 = snd[SEL0];
        float da1 = snd[1],    db1 = snd[SEL0+1];
        int   ja0 = sni[0],    jb0 = sni[SEL0];
        int   ja1 = sni[1],    jb1 = sni[SEL0+1];
        f_ld0 = (db0 < da0) ? db0 : da0;  f_j0 = (db0 < da0) ? jb0 : ja0;
        f_ld1 = (db1 < da1) ? db1 : da1;  f_j1 = (db1 < da1) ? jb1 : ja1;
        if (f_j0 < 0) f_j0 = i;
        if (f_j1 < 0) f_j1 = i;
        u0x = mimg(xi - X[3*f_j0+0], box, ibox);
        u0y = mimg(yi - X[3*f_j0+1], box, ibox);
        u0z = mimg(zi - X[3*f_j0+2], box, ibox);
        u1x = mimg(xi - X[3*f_j1+0], box, ibox);
        u1y = mimg(yi - X[3*f_j1+1], box, ibox);
        u1z = mimg(zi - X[3*f_j1+2], box, ibox);
        float id0 = 1.0f/(f_ld0 + FEPS), id1 = 1.0f/(f_ld1 + FEPS);
        r0x = u0x*id0; r0y = u0y*id0; r0z = u0z*id0;
        r1x = u1x*id1; r1y = u1y*id1; r1z = u1z*id1;
        f_s = r0x*r1x + r0y*r1y + r0z*r1z;
        float v2x = r1x - f_s*r0x, v2y = r1y - f_s*r0y, v2z = r1z - f_s*r0z;
        f_n2 = sqrtf(v2x*v2x + v2y*v2y + v2z*v2z);
        e2x = v2x/f_n2; e2y = v2y/f_n2; e2z = v2z/f_n2;
        float cx = r0y*r1z - r0z*r1y;
        float cy = r0z*r1x - r0x*r1z;
        float cz = r0x*r1y - r0y*r1x;
        f_n3 = sqrtf(cx*cx + cy*cy + cz*cz);
        e3x = cx/f_n3; e3y = cy/f_n3; e3z = cz/f_n3;
        sA[0]=r0x; sA[1]=r0y; sA[2]=r0z;
        sA[3]=e2x; sA[4]=e2y; sA[5]=e2z;
        sA[6]=e3x; sA[7]=e3y; sA[8]=e3z;
    }
    __syncthreads();

    // ---- angular features: f = (A . dm) / (d+eps)^2 ----
    if (tid < NANG) {
        int slot = (tid < ASEL0) ? tid : SEL0 + (tid - ASEL0);
        float d = snd[slot]; int j = sni[slot];
        float dx = 0, dy = 0, dz = 0;
        if (j >= 0) {
            dx = mimg(xi - X[3*j+0], box, ibox);
            dy = mimg(yi - X[3*j+1], box, ibox);
            dz = mimg(zi - X[3*j+2], box, ibox);
        }
        float de = d + FEPS;
        float q = 1.0f/(de*de);
        float wx = sA[0]*dx + sA[1]*dy + sA[2]*dz;
        float wy = sA[3]*dx + sA[4]*dy + sA[5]*dz;
        float wz = sA[6]*dx + sA[7]*dy + sA[8]*dz;
        sdesc[NNB + 3*tid + 0] = wx*q;
        sdesc[NNB + 3*tid + 1] = wy*q;
        sdesc[NNB + 3*tid + 2] = wz*q;
    }
    __syncthreads();

    // ---- MLP forward + backward (all 4 waves) ----
    const float* W0 = ti ? W0b : W0a;  const float* B0 = ti ? B0b : B0a;
    const float* W1 = ti ? W1b : W1a;  const float* B1 = ti ? B1b : B1a;
    const float* W2 = ti ? W2b : W2a;  const float* B2 = ti ? B2b : B2a;

    {   // layer 0: h1 = tanh(desc @ W0 + b0), 4-way split over DDIM
        float acc = 0.0f;
        for (int d = wv; d < DDIM; d += 4) acc = fmaf(sdesc[d], W0[d*HID + lane], acc);
        spart[wv][lane] = acc;
    }
    __syncthreads();
    if (tid < HID) {
        float a = spart[0][tid] + spart[1][tid] + spart[2][tid] + spart[3][tid] + B0[tid];
        sh1[tid] = tanhf(a);
    }
    __syncthreads();
    {   // layer 1: h2 = tanh(h1 @ W1 + b1), 4-way split over 64
        float acc = 0.0f;
        #pragma unroll
        for (int m = 0; m < 16; ++m) acc = fmaf(sh1[wv*16 + m], W1[(wv*16 + m)*HID + lane], acc);
        spart[wv][lane] = acc;
    }
    __syncthreads();
    if (tid < HID) {
        float a = spart[0][tid] + spart[1][tid] + spart[2][tid] + spart[3][tid] + B1[tid];
        float h2 = tanhf(a);
        sh2[tid] = h2;
        float w2 = W2[tid];
        float part = h2 * w2;
        #pragma unroll
        for (int o = 32; o > 0; o >>= 1) part += __shfl_down(part, o, 64);
        if (tid == 0) atomicAdd(&out[b], part + B2[0]);
        sdh2[tid] = (1.0f - h2*h2) * w2;
    }
    __syncthreads();
    {   // dh1 = (1-h1^2) * (W1 @ dh2), 4-way split
        float acc = 0.0f;
        #pragma unroll
        for (int m = 0; m < 16; ++m) acc = fmaf(W1[lane*HID + wv*16 + m], sdh2[wv*16 + m], acc);
        spart[wv][lane] = acc;
    }
    __syncthreads();
    if (tid < HID) {
        float a = spart[0][tid] + spart[1][tid] + spart[2][tid] + spart[3][tid];
        float h1 = sh1[tid];
        sdh1[tid] = (1.0f - h1*h1) * a;
    }
    __syncthreads();
    for (int d = tid; d < DDIM; d += BLOCK) {
        float acc = 0.0f;
        #pragma unroll
        for (int m = 0; m < HID; ++m) acc = fmaf(W0[d*HID + m], sdh1[m], acc);
        sg[d] = acc;
    }
    __syncthreads();

    // ---- gradient scatter: radial + angular direct terms; accumulate G ----
    float* Fout = out + B;
    if (tid < NNB) {
        float d = snd[tid]; int j = sni[tid];
        if (j >= 0) {
            float dx = mimg(xi - X[3*j+0], box, ibox);
            float dy = mimg(yi - X[3*j+1], box, ibox);
            float dz = mimg(zi - X[3*j+2], box, ibox);
            float gr = sg[tid];
            float de = d + FEPS;
            float coef = -gr / (d * de * de);
            float gx = coef*dx, gy = coef*dy, gz = coef*dz;
            int a = -1;
            if (tid < ASEL0) a = tid;
            else if (tid >= SEL0 && tid < SEL0 + ASEL1) a = ASEL0 + (tid - SEL0);
            if (a >= 0) {
                float q = 1.0f/(de*de);
                float gax = sg[NNB+3*a+0], gay = sg[NNB+3*a+1], gaz = sg[NNB+3*a+2];
                float wx = sA[0]*dx + sA[1]*dy + sA[2]*dz;
                float wy = sA[3]*dx + sA[4]*dy + sA[5]*dz;
                float wz = sA[6]*dx + sA[7]*dy + sA[8]*dz;
                float tx = sA[0]*gax + sA[3]*gay + sA[6]*gaz;
                float ty = sA[1]*gax + sA[4]*gay + sA[7]*gaz;
                float tz = sA[2]*gax + sA[5]*gay + sA[8]*gaz;
                float gw = gax*wx + gay*wy + gaz*wz;
                float c2 = -2.0f * gw * q / (de * d);
                gx += q*tx + c2*dx;
                gy += q*ty + c2*dy;
                gz += q*tz + c2*dz;
                atomicAdd(&sG[0], gax*dx*q); atomicAdd(&sG[1], gax*dy*q); atomicAdd(&sG[2], gax*dz*q);
                atomicAdd(&sG[3], gay*dx*q); atomicAdd(&sG[4], gay*dy*q); atomicAdd(&sG[5], gay*dz*q);
                atomicAdd(&sG[6], gaz*dx*q); atomicAdd(&sG[7], gaz*dy*q); atomicAdd(&sG[8], gaz*dz*q);
            }
            float* Fj = Fout + 3*((size_t)b*N + j);
            atomicAdd(&Fj[0], gx); atomicAdd(&Fj[1], gy); atomicAdd(&Fj[2], gz);
            atomicAdd(&sFi[0], -gx); atomicAdd(&sFi[1], -gy); atomicAdd(&sFi[2], -gz);
        }
    }
    __syncthreads();

    // ---- frame backward (thread 0) ----
    if (tid == 0 && f_j0 >= 0) {
        float g0x=sG[0], g0y=sG[1], g0z=sG[2];
        float g2x=sG[3], g2y=sG[4], g2z=sG[5];
        float g3x=sG[6], g3y=sG[7], g3z=sG[8];
        float d3 = g3x*e3x + g3y*e3y + g3z*e3z;
        float in3 = 1.0f/f_n3;
        float dcx = (g3x - d3*e3x)*in3;
        float dcy = (g3y - d3*e3y)*in3;
        float dcz = (g3z - d3*e3z)*in3;
        float gr0x = r1y*dcz - r1z*dcy;
        float gr0y = r1z*dcx - r1x*dcz;
        float gr0z = r1x*dcy - r1y*dcx;
        float gr1x = dcy*r0z - dcz*r0y;
        float gr1y = dcz*r0x - dcx*r0z;
        float gr1z = dcx*r0y - dcy*r0x;
        float d2 = g2x*e2x + g2y*e2y + g2z*e2z;
        float in2 = 1.0f/f_n2;
        float dvx = (g2x - d2*e2x)*in2;
        float dvy = (g2y - d2*e2y)*in2;
        float dvz = (g2z - d2*e2z)*in2;
        gr1x += dvx; gr1y += dvy; gr1z += dvz;
        gr0x -= f_s*dvx; gr0y -= f_s*dvy; gr0z -= f_s*dvz;
        float dss = -(dvx*r0x + dvy*r0y + dvz*r0z);
        gr0x += dss*r1x; gr0y += dss*r1y; gr0z += dss*r1z;
        gr1x += dss*r0x; gr1y += dss*r0y; gr1z += dss*r0z;
        gr0x += g0x; gr0y += g0y; gr0z += g0z;
        float de0 = f_ld0 + FEPS;
        float dot0 = gr0x*u0x + gr0y*u0y + gr0z*u0z;
        float k0 = dot0 / (f_ld0 * de0 * de0);
        float gu0x = gr0x/de0 - k0*u0x;
        float gu0y = gr0y/de0 - k0*u0y;
        float gu0z = gr0z/de0 - k0*u0z;
        float de1 = f_ld1 + FEPS;
        float dot1 = gr1x*u1x + gr1y*u1y + gr1z*u1z;
        float k1 = dot1 / (f_ld1 * de1 * de1);
        float gu1x = gr1x/de1 - k1*u1x;
        float gu1y = gr1y/de1 - k1*u1y;
        float gu1z = gr1z/de1 - k1*u1z;
        float* Fj0 = Fout + 3*((size_t)b*N + f_j0);
        atomicAdd(&Fj0[0], gu0x); atomicAdd(&Fj0[1], gu0y); atomicAdd(&Fj0[2], gu0z);
        float* Fj1 = Fout + 3*((size_t)b*N + f_j1);
        atomicAdd(&Fj1[0], gu1x); atomicAdd(&Fj1[1], gu1y); atomicAdd(&Fj1[2], gu1z);
        sFi[0] -= gu0x + gu1x;
        sFi[1] -= gu0y + gu1y;
        sFi[2] -= gu0z + gu1z;
    }
    __syncthreads();
    if (tid < 3) {
        atomicAdd(&Fout[3*((size_t)b*N + i) + tid], sFi[tid]);
    }
}

extern "C" void kernel_launch(void* const* d_in, const int* in_sizes, int n_in,
                              void* d_out, int out_size, void* d_ws, size_t ws_size,
                              hipStream_t stream) {
    const float* xyz  = (const float*)d_in[0];
    const int*   types = (const int*)d_in[1];
    const void*  boxp = d_in[2];
    int BN = in_sizes[1];              // B*N
    int B = out_size - 3*BN;           // out = energy(B) + forces(3*B*N)
    if (B < 1) B = 1;
    int N = BN / B;
    hipMemsetAsync(d_out, 0, (size_t)out_size * sizeof(float), stream);
    md_kernel<<<dim3(BN), dim3(BLOCK), 0, stream>>>(
        xyz, types, boxp,
        (const float*)d_in[3],  (const float*)d_in[4],
        (const float*)d_in[5],  (const float*)d_in[6],
        (const float*)d_in[7],  (const float*)d_in[8],
        (const float*)d_in[9],  (const float*)d_in[10],
        (const float*)d_in[11], (const float*)d_in[12],
        (const float*)d_in[13], (const float*)d_in[14],
        (float*)d_out, B, N);
}

// Round 4
// 311.394 us; speedup vs baseline: 1.3864x; 1.0395x over previous
//
#include <hip/hip_runtime.h>
#include <stdint.h>
#include <math.h>

#define BLOCK 256
#define SEL0 46
#define SEL1 92
#define ASEL0 16
#define ASEL1 32
#define NNB 138           // SEL0+SEL1
#define NANG 48           // ASEL0+ASEL1
#define DDIM 282          // NNB + 3*NANG
#define HID 64
#define FEPS 1e-16f
#define NPT 8             // atoms per thread (N=2048 / BLOCK)
#define CAP 128           // per-type candidate cap (wave-sortable)
#define NREP 16           // force-scatter replicas (2 per XCD)

__device__ __forceinline__ float mimg(float dx, float box, float ibox) {
    return dx - box * rintf(dx * ibox);   // jnp.round = round-half-even = rintf
}

// sum NREP replicas -> out.  out = [energy(B) | forces(3BN)]
__global__ __launch_bounds__(BLOCK)
void reduce_kernel(const float* __restrict__ rep, float* __restrict__ out,
                   int total, int Bc, int eoff, int rstride, int nrep)
{
    int e = blockIdx.x * BLOCK + threadIdx.x;
    if (e >= total) return;
    int src = (e < Bc) ? (eoff + e) : (e - Bc);
    float s = 0.0f;
    for (int r = 0; r < nrep; ++r) s += rep[(size_t)r * rstride + src];
    out[e] = s;
}

__global__ __launch_bounds__(BLOCK)
void md_kernel(const float* __restrict__ xyz, const int* __restrict__ types,
               const void* __restrict__ boxp,
               const float* __restrict__ W0a, const float* __restrict__ B0a,
               const float* __restrict__ W1a, const float* __restrict__ B1a,
               const float* __restrict__ W2a, const float* __restrict__ B2a,
               const float* __restrict__ W0b, const float* __restrict__ B0b,
               const float* __restrict__ W1b, const float* __restrict__ B1b,
               const float* __restrict__ W2b, const float* __restrict__ B2b,
               float* __restrict__ out, float* __restrict__ repbase,
               int nrep, int eoff, int rstride, int B, int N)
{
    const int atom = blockIdx.x;
    const int b = atom / N;
    const int i = atom - b * N;
    const int tid = threadIdx.x;
    const int wv = tid >> 6, lane = tid & 63;

    __shared__ unsigned long long A0[CAP], A1[CAP];
    __shared__ float snd[NNB];
    __shared__ int   sni[NNB];
    __shared__ float sdesc[DDIM];
    __shared__ float sg[DDIM];
    __shared__ float sA[9];
    __shared__ float sh1[HID], sh2[HID], sdh2[HID], sdh1[HID];
    __shared__ float spart[4][HID];
    __shared__ float sG[9];
    __shared__ float sFi[3];
    __shared__ int sCnt0, sCnt1, sTot1;

    // replica targets: forces at offset 0, energies at eoff (own cache line)
    float* Fout;   // forces base (indexed by 3*(b*N+j)+c)
    float* Eout;   // energy base (indexed by b)
    if (repbase) {
        float* base = repbase + (size_t)(blockIdx.x % nrep) * rstride;
        Fout = base; Eout = base + eoff;
    } else {
        Fout = out + B; Eout = out;
    }

    // box_size may arrive as int32 (python int scalar) or float32; decode.
    int ib_test = ((const int*)boxp)[0];
    float box = (ib_test > 0 && ib_test < 1000000) ? (float)ib_test
                                                   : ((const float*)boxp)[0];
    float ibox = 1.0f / box;

    const float* X = xyz + (size_t)b * N * 3;
    const int*   T = types + (size_t)b * N;
    const int ti = T[i];
    const float xi = X[3*i+0], yi = X[3*i+1], zi = X[3*i+2];

    // ---- per-thread distance keys in registers: rk = typebit<<31 | dist_bits ----
    uint32_t rk[NPT];
    #pragma unroll
    for (int jj = 0; jj < NPT; ++jj) {
        int j = jj * BLOCK + tid;
        uint32_t k = 0x7FFFFFFFu;           // self / pad: below no threshold
        if (j < N && j != i) {
            float dx = mimg(xi - X[3*j+0], box, ibox);
            float dy = mimg(yi - X[3*j+1], box, ibox);
            float dz = mimg(zi - X[3*j+2], box, ibox);
            float d = sqrtf(dx*dx + dy*dy + dz*dz);
            k = __float_as_uint(d) | (T[j] ? 0x80000000u : 0u);
        }
        rk[jj] = k;
    }

    // ---- per-type totals ----
    if (tid == 0) { sTot1 = 0; }
    __syncthreads();
    {
        uint32_t t1 = 0;
        #pragma unroll
        for (int jj = 0; jj < NPT; ++jj) t1 += (rk[jj] >> 31);
        #pragma unroll
        for (int o = 32; o > 0; o >>= 1) t1 += __shfl_down(t1, o, 64);
        if (lane == 0 && t1) atomicAdd(&sTot1, (int)t1);
    }
    __syncthreads();
    const int tot1 = sTot1;
    const int tot0 = (N - 1) - tot1;
    const int need0 = min(SEL0, tot0);
    const int need1 = min(SEL1, tot1);

    // ---- per-type radii via bisection: need_t <= count_t <= CAP ----
    const float vol = box * box * box;
    const float c43pi = 4.18879020f;   // 4/3*pi
    float R0 = cbrtf(0.5f * (need0 + CAP) * vol / (c43pi * fmaxf((float)tot0, 1.0f)));
    float R1 = cbrtf(0.5f * (need1 + CAP) * vol / (c43pi * fmaxf((float)tot1, 1.0f)));
    uint32_t Rb0 = __float_as_uint(R0), Rb1 = __float_as_uint(R1);
    float lo0 = 0.0f, hi0 = -1.0f, lo1 = 0.0f, hi1 = -1.0f;
    for (int it = 0; it < 20; ++it) {
        if (tid == 0) { sCnt0 = 0; sCnt1 = 0; }
        __syncthreads();
        uint32_t c0 = 0, c1 = 0;
        #pragma unroll
        for (int jj = 0; jj < NPT; ++jj) {
            uint32_t k = rk[jj];
            c0 += ((k < 0x80000000u) && (k < Rb0));
            c1 += ((k >= 0x80000000u) && ((k & 0x7FFFFFFFu) < Rb1));
        }
        uint32_t packed = c0 | (c1 << 16);
        #pragma unroll
        for (int o = 32; o > 0; o >>= 1) packed += __shfl_down(packed, o, 64);
        if (lane == 0 && packed) {
            atomicAdd(&sCnt0, (int)(packed & 0xFFFFu));
            atomicAdd(&sCnt1, (int)(packed >> 16));
        }
        __syncthreads();
        int cc0 = sCnt0, cc1 = sCnt1;
        bool done0 = (cc0 >= need0 && cc0 <= CAP);
        bool done1 = (cc1 >= need1 && cc1 <= CAP);
        if (done0 && done1) break;
        if (!done0) {
            if (cc0 < need0) { lo0 = R0; R0 = (hi0 > 0.0f) ? 0.5f*(lo0+hi0) : R0*1.3f; }
            else             { hi0 = R0; R0 = 0.5f*(lo0+hi0); }
            Rb0 = __float_as_uint(R0);
        }
        if (!done1) {
            if (cc1 < need1) { lo1 = R1; R1 = (hi1 > 0.0f) ? 0.5f*(lo1+hi1) : R1*1.3f; }
            else             { hi1 = R1; R1 = 0.5f*(lo1+hi1); }
            Rb1 = __float_as_uint(R1);
        }
        __syncthreads();
    }

    // ---- compact per-type candidates into A0 / A1 ----
    if (tid == 0) { sCnt0 = 0; sCnt1 = 0; }
    __syncthreads();
    #pragma unroll
    for (int jj = 0; jj < NPT; ++jj) {
        uint32_t k = rk[jj];
        uint32_t idx = (uint32_t)(jj * BLOCK + tid);
        if (k < 0x80000000u) {
            if (k < Rb0) {
                int pos = atomicAdd(&sCnt0, 1);
                if (pos < CAP) A0[pos] = ((unsigned long long)k << 32) | idx;
            }
        } else {
            uint32_t kk = k & 0x7FFFFFFFu;
            if (kk < Rb1) {
                int pos = atomicAdd(&sCnt1, 1);
                if (pos < CAP) A1[pos] = ((unsigned long long)kk << 32) | idx;
            }
        }
    }
    __syncthreads();
    const int c0 = min(sCnt0, CAP);
    const int c1 = min(sCnt1, CAP);
    if (tid < CAP) { if (tid >= c0) A0[tid] = ~0ull; }
    else { int t2 = tid - CAP; if (t2 >= c1) A1[t2] = ~0ull; }
    __syncthreads();

    // ---- wave-level register bitonic sort: wave0 -> A0, wave1 -> A1 ----
    if (wv < 2) {
        unsigned long long* A = (wv == 0) ? A0 : A1;
        unsigned long long v0 = A[lane], v1 = A[lane + 64];
        #pragma unroll
        for (int size = 2; size <= 128; size <<= 1) {
            #pragma unroll
            for (int stride = 64; stride > 0; stride >>= 1) {
                if (stride >= size) continue;
                if (stride == 64) {
                    unsigned long long mn = v0 < v1 ? v0 : v1;
                    unsigned long long mx = v0 < v1 ? v1 : v0;
                    v0 = mn; v1 = mx;
                } else {
                    bool keep_lo = (lane & stride) == 0;
                    bool asc0 = ((lane & size) == 0);
                    bool asc1 = (((lane + 64) & size) == 0);
                    unsigned long long o0 = __shfl_xor(v0, stride, 64);
                    unsigned long long o1 = __shfl_xor(v1, stride, 64);
                    v0 = (asc0 == keep_lo) ? (v0 < o0 ? v0 : o0) : (v0 > o0 ? v0 : o0);
                    v1 = (asc1 == keep_lo) ? (v1 < o1 ? v1 : o1) : (v1 > o1 ? v1 : o1);
                }
            }
        }
        A[lane] = v0; A[lane + 64] = v1;
    }
    if (tid < 9) sG[tid] = 0.0f;
    if (tid < 3) sFi[tid] = 0.0f;
    __syncthreads();

    // ---- neighbor tables + radial features 1/(d+eps) ----
    if (tid < NNB) {
        unsigned long long k; bool valid;
        if (tid < SEL0) { valid = (tid < c0); k = A0[tid]; }
        else            { int t2 = tid - SEL0; valid = (t2 < c1); k = A1[t2]; }
        float d = 1e30f; int j = -1;
        if (valid) {
            d = __uint_as_float((uint32_t)(k >> 32));
            j = (int)(uint32_t)(k & 0xFFFFFFFFull);
        }
        snd[tid] = d; sni[tid] = j;
        sdesc[tid] = 1.0f / (d + FEPS);
    }
    __syncthreads();

    // ---- local frame (thread 0; keep state in registers for backward) ----
    float f_ld0=1.0f, f_ld1=1.0f; int f_j0=-1, f_j1=-1;
    float r0x=0,r0y=0,r0z=0, r1x=0,r1y=0,r1z=0;
    float u0x=0,u0y=0,u0z=0, u1x=0,u1y=0,u1z=0;
    float f_s=0, f_n2=1, f_n3=1;
    float e2x=0,e2y=0,e2z=0, e3x=0,e3y=0,e3z=0;
    if (tid == 0) {
        float da0 = snd[0],    db0 = snd[SEL0];
        float da1 = snd[1],    db1 = snd[SEL0+1];
        int   ja0 = sni[0],    jb0 = sni[SEL0];
        int   ja1 = sni[1],    jb1 = sni[SEL0+1];
        f_ld0 = (db0 < da0) ? db0 : da0;  f_j0 = (db0 < da0) ? jb0 : ja0;
        f_ld1 = (db1 < da1) ? db1 : da1;  f_j1 = (db1 < da1) ? jb1 : ja1;
        if (f_j0 < 0) f_j0 = i;
        if (f_j1 < 0) f_j1 = i;
        u0x = mimg(xi - X[3*f_j0+0], box, ibox);
        u0y = mimg(yi - X[3*f_j0+1], box, ibox);
        u0z = mimg(zi - X[3*f_j0+2], box, ibox);
        u1x = mimg(xi - X[3*f_j1+0], box, ibox);
        u1y = mimg(yi - X[3*f_j1+1], box, ibox);
        u1z = mimg(zi - X[3*f_j1+2], box, ibox);
        float id0 = 1.0f/(f_ld0 + FEPS), id1 = 1.0f/(f_ld1 + FEPS);
        r0x = u0x*id0; r0y = u0y*id0; r0z = u0z*id0;
        r1x = u1x*id1; r1y = u1y*id1; r1z = u1z*id1;
        f_s = r0x*r1x + r0y*r1y + r0z*r1z;
        float v2x = r1x - f_s*r0x, v2y = r1y - f_s*r0y, v2z = r1z - f_s*r0z;
        f_n2 = sqrtf(v2x*v2x + v2y*v2y + v2z*v2z);
        e2x = v2x/f_n2; e2y = v2y/f_n2; e2z = v2z/f_n2;
        float cx = r0y*r1z - r0z*r1y;
        float cy = r0z*r1x - r0x*r1z;
        float cz = r0x*r1y - r0y*r1x;
        f_n3 = sqrtf(cx*cx + cy*cy + cz*cz);
        e3x = cx/f_n3; e3y = cy/f_n3; e3z = cz/f_n3;
        sA[0]=r0x; sA[1]=r0y; sA[2]=r0z;
        sA[3]=e2x; sA[4]=e2y; sA[5]=e2z;
        sA[6]=e3x; sA[7]=e3y; sA[8]=e3z;
    }
    __syncthreads();

    // ---- angular features: f = (A . dm) / (d+eps)^2 ----
    if (tid < NANG) {
        int slot = (tid < ASEL0) ? tid : SEL0 + (tid - ASEL0);
        float d = snd[slot]; int j = sni[slot];
        float dx = 0, dy = 0, dz = 0;
        if (j >= 0) {
            dx = mimg(xi - X[3*j+0], box, ibox);
            dy = mimg(yi - X[3*j+1], box, ibox);
            dz = mimg(zi - X[3*j+2], box, ibox);
        }
        float de = d + FEPS;
        float q = 1.0f/(de*de);
        float wx = sA[0]*dx + sA[1]*dy + sA[2]*dz;
        float wy = sA[3]*dx + sA[4]*dy + sA[5]*dz;
        float wz = sA[6]*dx + sA[7]*dy + sA[8]*dz;
        sdesc[NNB + 3*tid + 0] = wx*q;
        sdesc[NNB + 3*tid + 1] = wy*q;
        sdesc[NNB + 3*tid + 2] = wz*q;
    }
    __syncthreads();

    // ---- MLP forward + backward (all 4 waves) ----
    const float* W0 = ti ? W0b : W0a;  const float* B0 = ti ? B0b : B0a;
    const float* W1 = ti ? W1b : W1a;  const float* B1 = ti ? B1b : B1a;
    const float* W2 = ti ? W2b : W2a;  const float* B2 = ti ? B2b : B2a;

    {   // layer 0: h1 = tanh(desc @ W0 + b0), 4-way split over DDIM
        float acc = 0.0f;
        for (int d = wv; d < DDIM; d += 4) acc = fmaf(sdesc[d], W0[d*HID + lane], acc);
        spart[wv][lane] = acc;
    }
    __syncthreads();
    if (tid < HID) {
        float a = spart[0][tid] + spart[1][tid] + spart[2][tid] + spart[3][tid] + B0[tid];
        sh1[tid] = tanhf(a);
    }
    __syncthreads();
    {   // layer 1: h2 = tanh(h1 @ W1 + b1), 4-way split over 64
        float acc = 0.0f;
        #pragma unroll
        for (int m = 0; m < 16; ++m) acc = fmaf(sh1[wv*16 + m], W1[(wv*16 + m)*HID + lane], acc);
        spart[wv][lane] = acc;
    }
    __syncthreads();
    if (tid < HID) {
        float a = spart[0][tid] + spart[1][tid] + spart[2][tid] + spart[3][tid] + B1[tid];
        float h2 = tanhf(a);
        sh2[tid] = h2;
        float w2 = W2[tid];
        float part = h2 * w2;
        #pragma unroll
        for (int o = 32; o > 0; o >>= 1) part += __shfl_down(part, o, 64);
        if (tid == 0) atomicAdd(&Eout[b], part + B2[0]);
        sdh2[tid] = (1.0f - h2*h2) * w2;
    }
    __syncthreads();
    {   // dh1 = (1-h1^2) * (W1 @ dh2), 4-way split
        float acc = 0.0f;
        #pragma unroll
        for (int m = 0; m < 16; ++m) acc = fmaf(W1[lane*HID + wv*16 + m], sdh2[wv*16 + m], acc);
        spart[wv][lane] = acc;
    }
    __syncthreads();
    if (tid < HID) {
        float a = spart[0][tid] + spart[1][tid] + spart[2][tid] + spart[3][tid];
        float h1 = sh1[tid];
        sdh1[tid] = (1.0f - h1*h1) * a;
    }
    __syncthreads();
    for (int d = tid; d < DDIM; d += BLOCK) {
        float acc = 0.0f;
        #pragma unroll
        for (int m = 0; m < HID; ++m) acc = fmaf(W0[d*HID + m], sdh1[m], acc);
        sg[d] = acc;
    }
    __syncthreads();

    // ---- gradient scatter: radial + angular direct terms; accumulate G ----
    if (tid < NNB) {
        float d = snd[tid]; int j = sni[tid];
        if (j >= 0) {
            float dx = mimg(xi - X[3*j+0], box, ibox);
            float dy = mimg(yi - X[3*j+1], box, ibox);
            float dz = mimg(zi - X[3*j+2], box, ibox);
            float gr = sg[tid];
            float de = d + FEPS;
            float coef = -gr / (d * de * de);
            float gx = coef*dx, gy = coef*dy, gz = coef*dz;
            int a = -1;
            if (tid < ASEL0) a = tid;
            else if (tid >= SEL0 && tid < SEL0 + ASEL1) a = ASEL0 + (tid - SEL0);
            if (a >= 0) {
                float q = 1.0f/(de*de);
                float gax = sg[NNB+3*a+0], gay = sg[NNB+3*a+1], gaz = sg[NNB+3*a+2];
                float wx = sA[0]*dx + sA[1]*dy + sA[2]*dz;
                float wy = sA[3]*dx + sA[4]*dy + sA[5]*dz;
                float wz = sA[6]*dx + sA[7]*dy + sA[8]*dz;
                float tx = sA[0]*gax + sA[3]*gay + sA[6]*gaz;
                float ty = sA[1]*gax + sA[4]*gay + sA[7]*gaz;
                float tz = sA[2]*gax + sA[5]*gay + sA[8]*gaz;
                float gw = gax*wx + gay*wy + gaz*wz;
                float c2 = -2.0f * gw * q / (de * d);
                gx += q*tx + c2*dx;
                gy += q*ty + c2*dy;
                gz += q*tz + c2*dz;
                atomicAdd(&sG[0], gax*dx*q); atomicAdd(&sG[1], gax*dy*q); atomicAdd(&sG[2], gax*dz*q);
                atomicAdd(&sG[3], gay*dx*q); atomicAdd(&sG[4], gay*dy*q); atomicAdd(&sG[5], gay*dz*q);
                atomicAdd(&sG[6], gaz*dx*q); atomicAdd(&sG[7], gaz*dy*q); atomicAdd(&sG[8], gaz*dz*q);
            }
            float* Fj = Fout + 3*((size_t)b*N + j);
            atomicAdd(&Fj[0], gx); atomicAdd(&Fj[1], gy); atomicAdd(&Fj[2], gz);
            atomicAdd(&sFi[0], -gx); atomicAdd(&sFi[1], -gy); atomicAdd(&sFi[2], -gz);
        }
    }
    __syncthreads();

    // ---- frame backward (thread 0) ----
    if (tid == 0 && f_j0 >= 0) {
        float g0x=sG[0], g0y=sG[1], g0z=sG[2];
        float g2x=sG[3], g2y=sG[4], g2z=sG[5];
        float g3x=sG[6], g3y=sG[7], g3z=sG[8];
        float d3 = g3x*e3x + g3y*e3y + g3z*e3z;
        float in3 = 1.0f/f_n3;
        float dcx = (g3x - d3*e3x)*in3;
        float dcy = (g3y - d3*e3y)*in3;
        float dcz = (g3z - d3*e3z)*in3;
        float gr0x = r1y*dcz - r1z*dcy;
        float gr0y = r1z*dcx - r1x*dcz;
        float gr0z = r1x*dcy - r1y*dcx;
        float gr1x = dcy*r0z - dcz*r0y;
        float gr1y = dcz*r0x - dcx*r0z;
        float gr1z = dcx*r0y - dcy*r0x;
        float d2 = g2x*e2x + g2y*e2y + g2z*e2z;
        float in2 = 1.0f/f_n2;
        float dvx = (g2x - d2*e2x)*in2;
        float dvy = (g2y - d2*e2y)*in2;
        float dvz = (g2z - d2*e2z)*in2;
        gr1x += dvx; gr1y += dvy; gr1z += dvz;
        gr0x -= f_s*dvx; gr0y -= f_s*dvy; gr0z -= f_s*dvz;
        float dss = -(dvx*r0x + dvy*r0y + dvz*r0z);
        gr0x += dss*r1x; gr0y += dss*r1y; gr0z += dss*r1z;
        gr1x += dss*r0x; gr1y += dss*r0y; gr1z += dss*r0z;
        gr0x += g0x; gr0y += g0y; gr0z += g0z;
        float de0 = f_ld0 + FEPS;
        float dot0 = gr0x*u0x + gr0y*u0y + gr0z*u0z;
        float k0 = dot0 / (f_ld0 * de0 * de0);
        float gu0x = gr0x/de0 - k0*u0x;
        float gu0y = gr0y/de0 - k0*u0y;
        float gu0z = gr0z/de0 - k0*u0z;
        float de1 = f_ld1 + FEPS;
        float dot1 = gr1x*u1x + gr1y*u1y + gr1z*u1z;
        float k1 = dot1 / (f_ld1 * de1 * de1);
        float gu1x = gr1x/de1 - k1*u1x;
        float gu1y = gr1y/de1 - k1*u1y;
        float gu1z = gr1z/de1 - k1*u1z;
        float* Fj0 = Fout + 3*((size_t)b*N + f_j0);
        atomicAdd(&Fj0[0], gu0x); atomicAdd(&Fj0[1], gu0y); atomicAdd(&Fj0[2], gu0z);
        float* Fj1 = Fout + 3*((size_t)b*N + f_j1);
        atomicAdd(&Fj1[0], gu1x); atomicAdd(&Fj1[1], gu1y); atomicAdd(&Fj1[2], gu1z);
        sFi[0] -= gu0x + gu1x;
        sFi[1] -= gu0y + gu1y;
        sFi[2] -= gu0z + gu1z;
    }
    __syncthreads();
    if (tid < 3) {
        atomicAdd(&Fout[3*((size_t)b*N + i) + tid], sFi[tid]);
    }
}

extern "C" void kernel_launch(void* const* d_in, const int* in_sizes, int n_in,
                              void* d_out, int out_size, void* d_ws, size_t ws_size,
                              hipStream_t stream) {
    const float* xyz  = (const float*)d_in[0];
    const int*   types = (const int*)d_in[1];
    const void*  boxp = d_in[2];
    int BN = in_sizes[1];              // B*N
    int B = out_size - 3*BN;           // out = energy(B) + forces(3*B*N)
    if (B < 1) B = 1;
    int N = BN / B;

    // replica layout: [forces 3BN (padded to 32)] [energies B (padded to 32)]
    int eoff = ((3 * BN + 31) / 32) * 32;          // 128B-aligned energy offset
    int rstride = eoff + ((B + 31) / 32) * 32;
    int nrep = NREP;
    size_t need = (size_t)nrep * rstride * sizeof(float);
    if (need > ws_size) {
        nrep = (int)(ws_size / ((size_t)rstride * sizeof(float)));
        if (nrep > NREP) nrep = NREP;
    }
    float* rep = (nrep >= 1) ? (float*)d_ws : nullptr;

    if (rep) {
        hipMemsetAsync(d_ws, 0, (size_t)nrep * rstride * sizeof(float), stream);
    } else {
        hipMemsetAsync(d_out, 0, (size_t)out_size * sizeof(float), stream);
    }

    md_kernel<<<dim3(BN), dim3(BLOCK), 0, stream>>>(
        xyz, types, boxp,
        (const float*)d_in[3],  (const float*)d_in[4],
        (const float*)d_in[5],  (const float*)d_in[6],
        (const float*)d_in[7],  (const float*)d_in[8],
        (const float*)d_in[9],  (const float*)d_in[10],
        (const float*)d_in[11], (const float*)d_in[12],
        (const float*)d_in[13], (const float*)d_in[14],
        (float*)d_out, rep, nrep > 0 ? nrep : 1, eoff, rstride, B, N);

    if (rep) {
        int total = out_size;
        int nb = (total + BLOCK - 1) / BLOCK;
        reduce_kernel<<<dim3(nb), dim3(BLOCK), 0, stream>>>(
            rep, (float*)d_out, total, B, eoff, rstride, nrep);
    }
}